// Round 1
// baseline (327.646 us; speedup 1.0000x reference)
//
#include <hip/hip_runtime.h>
#include <hip/hip_bf16.h>

#define BB 4
#define SS 2048
#define DM 1024
#define DN 64

typedef short short8 __attribute__((ext_vector_type(8)));
typedef float f32x4 __attribute__((ext_vector_type(4)));
typedef unsigned int uint4v __attribute__((ext_vector_type(4)));

__device__ __forceinline__ unsigned short f2bf(float f) {
    union { float f; unsigned u; } v; v.f = f;
    unsigned r = v.u + 0x7fffu + ((v.u >> 16) & 1u);
    return (unsigned short)(r >> 16);
}

// ---------------------------------------------------------------------------
// Projection: out = x @ w^T + b for x in {q,k,v}; M=8192, N=64, K=1024.
// qp/kp stored row-major bf16 [8192][64]; vp stored transposed [4][64][2048]
// so the flash kernel's PV B-fragments are contiguous.
// ---------------------------------------------------------------------------
__global__ __launch_bounds__(256) void proj_kernel(
    const float* __restrict__ q, const float* __restrict__ k, const float* __restrict__ v,
    const float* __restrict__ wq, const float* __restrict__ bq,
    const float* __restrict__ wk, const float* __restrict__ bk,
    const float* __restrict__ wvp, const float* __restrict__ bvp,
    unsigned short* __restrict__ qp, unsigned short* __restrict__ kp,
    unsigned short* __restrict__ vpT)
{
    __shared__ unsigned short A_lds[64][40];  // +8 pad: 80B row stride, 16B aligned
    __shared__ unsigned short B_lds[64][40];

    const int tid  = threadIdx.x;
    const int proj = blockIdx.y;
    const int m0   = blockIdx.x * 64;

    const float* x    = (proj == 0) ? q  : (proj == 1) ? k  : v;
    const float* w    = (proj == 0) ? wq : (proj == 1) ? wk : wvp;
    const float* bias = (proj == 0) ? bq : (proj == 1) ? bk : bvp;

    const int lane  = tid & 63;
    const int wv_id = tid >> 6;
    const int l16   = lane & 15;
    const int quad  = lane >> 4;

    const int srow = tid >> 2;        // 0..63
    const int skk  = (tid & 3) * 8;   // 0,8,16,24

    f32x4 acc[4];
#pragma unroll
    for (int t = 0; t < 4; t++) acc[t] = (f32x4){0.f, 0.f, 0.f, 0.f};

    for (int kb = 0; kb < DM; kb += 32) {
        __syncthreads();
        {
            const float* src = &x[(size_t)(m0 + srow) * DM + kb + skk];
            float4 f0 = *(const float4*)(src);
            float4 f1 = *(const float4*)(src + 4);
            unsigned short ta[8] = { f2bf(f0.x), f2bf(f0.y), f2bf(f0.z), f2bf(f0.w),
                                     f2bf(f1.x), f2bf(f1.y), f2bf(f1.z), f2bf(f1.w) };
            *(uint4v*)&A_lds[srow][skk] = *(uint4v*)ta;

            const float* srcw = &w[(size_t)srow * DM + kb + skk];
            float4 g0 = *(const float4*)(srcw);
            float4 g1 = *(const float4*)(srcw + 4);
            unsigned short tb[8] = { f2bf(g0.x), f2bf(g0.y), f2bf(g0.z), f2bf(g0.w),
                                     f2bf(g1.x), f2bf(g1.y), f2bf(g1.z), f2bf(g1.w) };
            *(uint4v*)&B_lds[srow][skk] = *(uint4v*)tb;
        }
        __syncthreads();

        // A-frag: A[m=l16][k=quad*8+j]; B-frag: B[k=quad*8+j][n=l16] = w[n][k]
        short8 a = *(const short8*)&A_lds[wv_id * 16 + l16][quad * 8];
#pragma unroll
        for (int t = 0; t < 4; t++) {
            short8 b = *(const short8*)&B_lds[t * 16 + l16][quad * 8];
            acc[t] = __builtin_amdgcn_mfma_f32_16x16x32_bf16(a, b, acc[t], 0, 0, 0);
        }
    }

    // epilogue: C/D layout col = l16 (+16t), row = quad*4 + r
#pragma unroll
    for (int t = 0; t < 4; t++) {
        int n = t * 16 + l16;
        float bb_ = bias[n];
#pragma unroll
        for (int r = 0; r < 4; r++) {
            int grow = m0 + wv_id * 16 + quad * 4 + r;
            unsigned short h = f2bf(acc[t][r] + bb_);
            if (proj == 0)      qp[(size_t)grow * DN + n] = h;
            else if (proj == 1) kp[(size_t)grow * DN + n] = h;
            else {
                int bb = grow >> 11, s = grow & 2047;
                vpT[((size_t)bb * DN + n) * SS + s] = h;
            }
        }
    }
}

// ---------------------------------------------------------------------------
// Flash attention: per block = (batch, 32 q rows), 2 waves x 16 q rows.
// Key-tiles of 64. Mask applied in fp32 (argmax decided by ~1e2 score gaps).
// ---------------------------------------------------------------------------
__global__ __launch_bounds__(128) void flash_kernel(
    const float* __restrict__ mask,
    const unsigned short* __restrict__ qp,
    const unsigned short* __restrict__ kp,
    const unsigned short* __restrict__ vpT,
    float* __restrict__ out)
{
    __shared__ unsigned short qp_lds[32][72];     // +8 pad rows -> 2-way bank alias (free)
    __shared__ unsigned short kp_lds[64][72];
    __shared__ unsigned short vpT_lds[64][72];
    __shared__ unsigned short p_lds[2][16][72];

    const int tid  = threadIdx.x;
    const int b    = blockIdx.y;
    const int q0   = blockIdx.x * 32;
    const int lane = tid & 63;
    const int wv   = tid >> 6;
    const int l16  = lane & 15;
    const int quad = lane >> 4;

    // stage qp tile (32 rows x 64 cols bf16)
    for (int c = tid; c < 32 * 8; c += 128) {
        int row = c >> 3, col8 = (c & 7) * 8;
        *(uint4v*)&qp_lds[row][col8] =
            *(const uint4v*)&qp[((size_t)(b * SS + q0 + row)) * DN + col8];
    }
    __syncthreads();

    short8 aq0 = *(const short8*)&qp_lds[wv * 16 + l16][quad * 8];
    short8 aq1 = *(const short8*)&qp_lds[wv * 16 + l16][32 + quad * 8];

    float m_r[4] = { -__builtin_inff(), -__builtin_inff(),
                     -__builtin_inff(), -__builtin_inff() };
    float l_r[4] = { 0.f, 0.f, 0.f, 0.f };
    f32x4 Oacc[4];
#pragma unroll
    for (int t = 0; t < 4; t++) Oacc[t] = (f32x4){0.f, 0.f, 0.f, 0.f};

    const size_t mbase = ((size_t)b * SS + (size_t)(q0 + wv * 16 + quad * 4)) * SS;

    for (int k0 = 0; k0 < SS; k0 += 64) {
        __syncthreads();
        for (int c = tid; c < 64 * 8; c += 128) {
            int row = c >> 3, col8 = (c & 7) * 8;
            *(uint4v*)&kp_lds[row][col8] =
                *(const uint4v*)&kp[((size_t)(b * SS + k0 + row)) * DN + col8];
        }
        for (int c = tid; c < 64 * 8; c += 128) {
            int feat = c >> 3, key8 = (c & 7) * 8;
            *(uint4v*)&vpT_lds[feat][key8] =
                *(const uint4v*)&vpT[((size_t)(b * DN + feat)) * SS + k0 + key8];
        }
        __syncthreads();

        // fp32 mask (coalesced 64B segments per quad; every line fully consumed)
        float mk[4][4];
#pragma unroll
        for (int t = 0; t < 4; t++)
#pragma unroll
            for (int r = 0; r < 4; r++)
                mk[t][r] = mask[mbase + (size_t)r * SS + k0 + t * 16 + l16];

        // S = qp . kp^T  (C layout: key = t*16 + l16, qrow = quad*4 + r)
        f32x4 sc[4];
#pragma unroll
        for (int t = 0; t < 4; t++) {
            short8 bk0 = *(const short8*)&kp_lds[t * 16 + l16][quad * 8];
            short8 bk1 = *(const short8*)&kp_lds[t * 16 + l16][32 + quad * 8];
            f32x4 z = (f32x4){0.f, 0.f, 0.f, 0.f};
            z = __builtin_amdgcn_mfma_f32_16x16x32_bf16(aq0, bk0, z, 0, 0, 0);
            z = __builtin_amdgcn_mfma_f32_16x16x32_bf16(aq1, bk1, z, 0, 0, 0);
            sc[t] = z;
        }

        // online softmax per accumulator reg (one q row per reg)
#pragma unroll
        for (int r = 0; r < 4; r++) {
            float s[4];
            float tmax = -__builtin_inff();
#pragma unroll
            for (int t = 0; t < 4; t++) {
                s[t] = sc[t][r] * 0.125f - 1e9f * mk[t][r];
                tmax = fmaxf(tmax, s[t]);
            }
#pragma unroll
            for (int off = 8; off >= 1; off >>= 1)
                tmax = fmaxf(tmax, __shfl_xor(tmax, off, 16));
            float mnew  = fmaxf(m_r[r], tmax);
            float alpha = __expf(m_r[r] - mnew);
            m_r[r] = mnew;
            float rs = 0.f;
#pragma unroll
            for (int t = 0; t < 4; t++) {
                float pv = __expf(s[t] - mnew);
                rs += pv;
                p_lds[wv][quad * 4 + r][t * 16 + l16] = f2bf(pv);
            }
#pragma unroll
            for (int off = 8; off >= 1; off >>= 1)
                rs += __shfl_xor(rs, off, 16);
            l_r[r] = l_r[r] * alpha + rs;
#pragma unroll
            for (int tf = 0; tf < 4; tf++)
                Oacc[tf][r] *= alpha;
        }
        __syncthreads();  // P C-layout -> A-layout roundtrip

        short8 ap0 = *(const short8*)&p_lds[wv][l16][quad * 8];
        short8 ap1 = *(const short8*)&p_lds[wv][l16][32 + quad * 8];
#pragma unroll
        for (int tf = 0; tf < 4; tf++) {
            short8 bv0 = *(const short8*)&vpT_lds[tf * 16 + l16][quad * 8];
            short8 bv1 = *(const short8*)&vpT_lds[tf * 16 + l16][32 + quad * 8];
            Oacc[tf] = __builtin_amdgcn_mfma_f32_16x16x32_bf16(ap0, bv0, Oacc[tf], 0, 0, 0);
            Oacc[tf] = __builtin_amdgcn_mfma_f32_16x16x32_bf16(ap1, bv1, Oacc[tf], 0, 0, 0);
        }
    }

    // epilogue: O[q][feat] / l
#pragma unroll
    for (int tf = 0; tf < 4; tf++)
#pragma unroll
        for (int r = 0; r < 4; r++) {
            size_t row = (size_t)b * SS + q0 + wv * 16 + quad * 4 + r;
            out[row * DN + tf * 16 + l16] = Oacc[tf][r] / l_r[r];
        }
}

extern "C" void kernel_launch(void* const* d_in, const int* in_sizes, int n_in,
                              void* d_out, int out_size, void* d_ws, size_t ws_size,
                              hipStream_t stream) {
    const float* q    = (const float*)d_in[0];
    const float* k    = (const float*)d_in[1];
    const float* v    = (const float*)d_in[2];
    const float* mask = (const float*)d_in[3];
    const float* wq   = (const float*)d_in[4];
    const float* bq   = (const float*)d_in[5];
    const float* wk   = (const float*)d_in[6];
    const float* bk   = (const float*)d_in[7];
    const float* wv   = (const float*)d_in[8];
    const float* bv   = (const float*)d_in[9];
    float* out = (float*)d_out;

    unsigned short* qp  = (unsigned short*)d_ws;               // [8192][64] bf16
    unsigned short* kp  = qp + (size_t)BB * SS * DN;           // [8192][64] bf16
    unsigned short* vpT = kp + (size_t)BB * SS * DN;           // [4][64][2048] bf16

    proj_kernel<<<dim3(128, 3), 256, 0, stream>>>(q, k, v, wq, bq, wk, bk, wv, bv,
                                                  qp, kp, vpT);
    flash_kernel<<<dim3(64, 4), 128, 0, stream>>>(mask, qp, kp, vpT, out);
}

// Round 2
// 226.624 us; speedup vs baseline: 1.4458x; 1.4458x over previous
//
#include <hip/hip_runtime.h>
#include <hip/hip_bf16.h>

#define BB 4
#define SS 2048
#define DM 1024
#define DN 64

typedef short short8 __attribute__((ext_vector_type(8)));
typedef float f32x4 __attribute__((ext_vector_type(4)));
typedef unsigned short ushort;

__device__ __forceinline__ ushort f2bf(float f) {
    union { float f; unsigned u; } v; v.f = f;
    unsigned r = v.u + 0x7fffu + ((v.u >> 16) & 1u);
    return (ushort)(r >> 16);
}

// ---------------------------------------------------------------------------
// prep_w: convert w_q|w_k|w_v (each [64][1024] fp32) to bf16, same layout.
// ---------------------------------------------------------------------------
__global__ __launch_bounds__(256) void prep_w(
    const float* __restrict__ wq, const float* __restrict__ wk,
    const float* __restrict__ wv, ushort* __restrict__ w_bf)
{
    int i = blockIdx.x * 256 + threadIdx.x;          // 49152 threads, 4 floats each
    int p = i >> 14;                                  // 16384 float4 per proj
    int j = (i & 16383) * 4;
    const float* src = (p == 0) ? wq : (p == 1) ? wk : wv;
    float4 f = *(const float4*)(src + j);
    ushort o[4] = { f2bf(f.x), f2bf(f.y), f2bf(f.z), f2bf(f.w) };
    *(unsigned long long*)(w_bf + p * 65536 + j) = *(unsigned long long*)o;
}

// ---------------------------------------------------------------------------
// proj: out = x @ w^T + b. Barrier-free: A-frags direct from global fp32,
// B-frags direct from bf16 w (L2-hot). One wave = 16 output rows, full K.
// qp/kp row-major bf16 [8192][64]; vp transposed [4][64][2048].
// ---------------------------------------------------------------------------
__global__ __launch_bounds__(128) void proj_kernel(
    const float* __restrict__ q, const float* __restrict__ k, const float* __restrict__ v,
    const ushort* __restrict__ w_bf,
    const float* __restrict__ bq, const float* __restrict__ bk, const float* __restrict__ bvp,
    ushort* __restrict__ qp, ushort* __restrict__ kp, ushort* __restrict__ vpT)
{
    const int tid  = threadIdx.x;
    const int proj = blockIdx.y;
    const int wv_id = tid >> 6;
    const int lane  = tid & 63;
    const int l16   = lane & 15;
    const int quad  = lane >> 4;
    const int g     = blockIdx.x * 2 + wv_id;   // 0..511 row-group
    const int m0    = g * 16;

    const float* x     = (proj == 0) ? q  : (proj == 1) ? k  : v;
    const ushort* wb   = w_bf + proj * 65536;
    const float* bias  = (proj == 0) ? bq : (proj == 1) ? bk : bvp;

    const float* arow = x + (size_t)(m0 + l16) * DM + quad * 8;

    f32x4 acc[4];
#pragma unroll
    for (int t = 0; t < 4; t++) acc[t] = (f32x4){0.f, 0.f, 0.f, 0.f};

#pragma unroll 2
    for (int kb = 0; kb < DM; kb += 32) {
        float4 f0 = *(const float4*)(arow + kb);
        float4 f1 = *(const float4*)(arow + kb + 4);
        ushort ta[8] = { f2bf(f0.x), f2bf(f0.y), f2bf(f0.z), f2bf(f0.w),
                         f2bf(f1.x), f2bf(f1.y), f2bf(f1.z), f2bf(f1.w) };
        short8 a = *(short8*)ta;
#pragma unroll
        for (int t = 0; t < 4; t++) {
            short8 b = *(const short8*)(wb + (size_t)(t * 16 + l16) * DM + kb + quad * 8);
            acc[t] = __builtin_amdgcn_mfma_f32_16x16x32_bf16(a, b, acc[t], 0, 0, 0);
        }
    }

    // C/D layout: n = t*16 + l16, row = quad*4 + r
#pragma unroll
    for (int t = 0; t < 4; t++) {
        int n = t * 16 + l16;
        float bb_ = bias[n];
#pragma unroll
        for (int r = 0; r < 4; r++) {
            int grow = m0 + quad * 4 + r;
            ushort h = f2bf(acc[t][r] + bb_);
            if (proj == 0)      qp[(size_t)grow * DN + n] = h;
            else if (proj == 1) kp[(size_t)grow * DN + n] = h;
            else {
                int bb = grow >> 11, s = grow & 2047;
                vpT[((size_t)bb * DN + n) * SS + s] = h;
            }
        }
    }
}

// ---------------------------------------------------------------------------
// flash: barrier-free. One wave = 16 q rows x one key-slice. All MFMA frags
// loaded directly from global (bf16, 16B/lane). P roundtrip via wave-private
// LDS. Mask applied in fp32. Writes unnormalized partial (O, m, l).
// ---------------------------------------------------------------------------
__global__ __launch_bounds__(256, 4) void flash_kernel(
    const float* __restrict__ mask,
    const ushort* __restrict__ qp,
    const ushort* __restrict__ kp,
    const ushort* __restrict__ vpT,
    float* __restrict__ part_O,     // [split][8192][64]
    float* __restrict__ part_ml,    // [split][8192][2]
    int nslice, int keys_per_slice)
{
    __shared__ __align__(16) ushort p_lds[4][16][80];  // 160B row stride: quads spread 8 banks

    const int tid  = threadIdx.x;
    const int wv   = tid >> 6;
    const int lane = tid & 63;
    const int l16  = lane & 15;
    const int quad = lane >> 4;

    const int gw     = blockIdx.x * 4 + wv;       // global wave id
    const int qg     = gw & 127;                  // q-group within batch (128/batch)
    const int rest   = gw >> 7;
    const int slice  = rest % nslice;
    const int b      = rest / nslice;

    // Q fragments (A-layout), direct from global
    const ushort* qbase = qp + ((size_t)b * SS + qg * 16 + l16) * DN + quad * 8;
    short8 aq0 = *(const short8*)(qbase);
    short8 aq1 = *(const short8*)(qbase + 32);

    float m_r[4] = { -__builtin_inff(), -__builtin_inff(),
                     -__builtin_inff(), -__builtin_inff() };
    float l_r[4] = { 0.f, 0.f, 0.f, 0.f };
    f32x4 Oacc[4];
#pragma unroll
    for (int t = 0; t < 4; t++) Oacc[t] = (f32x4){0.f, 0.f, 0.f, 0.f};

    const size_t mrow0 = ((size_t)b * SS + qg * 16 + quad * 4) * SS;
    const int k_begin = slice * keys_per_slice;
    const int k_end   = k_begin + keys_per_slice;

    for (int k0 = k_begin; k0 < k_end; k0 += 64) {
        // fp32 mask loads (argmax decided by ~1e2 score gaps -> must stay fp32)
        float mk[4][4];
#pragma unroll
        for (int t = 0; t < 4; t++)
#pragma unroll
            for (int r = 0; r < 4; r++)
                mk[t][r] = mask[mrow0 + (size_t)r * SS + k0 + t * 16 + l16];

        // S = qp . kp^T ; B-frags direct from global kp (row-major)
        f32x4 sc[4];
#pragma unroll
        for (int t = 0; t < 4; t++) {
            const ushort* kb_ = kp + ((size_t)b * SS + k0 + t * 16 + l16) * DN + quad * 8;
            short8 bk0 = *(const short8*)(kb_);
            short8 bk1 = *(const short8*)(kb_ + 32);
            f32x4 z = (f32x4){0.f, 0.f, 0.f, 0.f};
            z = __builtin_amdgcn_mfma_f32_16x16x32_bf16(aq0, bk0, z, 0, 0, 0);
            z = __builtin_amdgcn_mfma_f32_16x16x32_bf16(aq1, bk1, z, 0, 0, 0);
            sc[t] = z;
        }

        // online softmax per accumulator reg (one q row per reg)
#pragma unroll
        for (int r = 0; r < 4; r++) {
            float s[4];
            float tmax = -__builtin_inff();
#pragma unroll
            for (int t = 0; t < 4; t++) {
                s[t] = sc[t][r] * 0.125f - 1e9f * mk[t][r];
                tmax = fmaxf(tmax, s[t]);
            }
#pragma unroll
            for (int off = 8; off >= 1; off >>= 1)
                tmax = fmaxf(tmax, __shfl_xor(tmax, off, 16));
            float mnew  = fmaxf(m_r[r], tmax);
            float alpha = __expf(m_r[r] - mnew);
            m_r[r] = mnew;
            float rs = 0.f;
#pragma unroll
            for (int t = 0; t < 4; t++) {
                float pv = __expf(s[t] - mnew);
                rs += pv;
                p_lds[wv][quad * 4 + r][t * 16 + l16] = f2bf(pv);
            }
#pragma unroll
            for (int off = 8; off >= 1; off >>= 1)
                rs += __shfl_xor(rs, off, 16);
            l_r[r] = l_r[r] * alpha + rs;
#pragma unroll
            for (int tf = 0; tf < 4; tf++)
                Oacc[tf][r] *= alpha;
        }
        // wave-private LDS roundtrip: in-order DS pipe, no barrier needed

        short8 ap0 = *(const short8*)&p_lds[wv][l16][quad * 8];
        short8 ap1 = *(const short8*)&p_lds[wv][l16][32 + quad * 8];
#pragma unroll
        for (int tf = 0; tf < 4; tf++) {
            const ushort* vb_ = vpT + ((size_t)b * DN + tf * 16 + l16) * SS + k0 + quad * 8;
            short8 bv0 = *(const short8*)(vb_);
            short8 bv1 = *(const short8*)(vb_ + 32);
            Oacc[tf] = __builtin_amdgcn_mfma_f32_16x16x32_bf16(ap0, bv0, Oacc[tf], 0, 0, 0);
            Oacc[tf] = __builtin_amdgcn_mfma_f32_16x16x32_bf16(ap1, bv1, Oacc[tf], 0, 0, 0);
        }
    }

    // store partials (unnormalized O, plus m and l)
    const int rowg = (b * SS + qg * 16) + quad * 4;   // global row base for this quad
#pragma unroll
    for (int r = 0; r < 4; r++) {
        size_t row = (size_t)rowg + r;
        if (l16 == 0) {
            part_ml[((size_t)slice * (BB * SS) + row) * 2 + 0] = m_r[r];
            part_ml[((size_t)slice * (BB * SS) + row) * 2 + 1] = l_r[r];
        }
#pragma unroll
        for (int tf = 0; tf < 4; tf++)
            part_O[((size_t)slice * (BB * SS) + row) * DN + tf * 16 + l16] = Oacc[tf][r];
    }
}

// ---------------------------------------------------------------------------
// combine: merge nslice partials per row; normalize.
// ---------------------------------------------------------------------------
__global__ __launch_bounds__(256) void combine_kernel(
    const float* __restrict__ part_O, const float* __restrict__ part_ml,
    float* __restrict__ out, int nslice)
{
    const int tid = threadIdx.x;
    const int row = blockIdx.x * 4 + (tid >> 6);
    const int f   = tid & 63;

    float ms[8], ls[8];
    float M = -__builtin_inff();
    for (int i = 0; i < nslice; i++) {
        ms[i] = part_ml[((size_t)i * (BB * SS) + row) * 2 + 0];
        ls[i] = part_ml[((size_t)i * (BB * SS) + row) * 2 + 1];
        M = fmaxf(M, ms[i]);
    }
    float L = 0.f, acc = 0.f;
    for (int i = 0; i < nslice; i++) {
        float e = __expf(ms[i] - M);
        L += e * ls[i];
        acc += e * part_O[((size_t)i * (BB * SS) + row) * DN + f];
    }
    out[(size_t)row * DN + f] = acc / L;
}

extern "C" void kernel_launch(void* const* d_in, const int* in_sizes, int n_in,
                              void* d_out, int out_size, void* d_ws, size_t ws_size,
                              hipStream_t stream) {
    const float* q    = (const float*)d_in[0];
    const float* k    = (const float*)d_in[1];
    const float* v    = (const float*)d_in[2];
    const float* mask = (const float*)d_in[3];
    const float* wq   = (const float*)d_in[4];
    const float* bq   = (const float*)d_in[5];
    const float* wk   = (const float*)d_in[6];
    const float* bk   = (const float*)d_in[7];
    const float* wv   = (const float*)d_in[8];
    const float* bv   = (const float*)d_in[9];
    float* out = (float*)d_out;

    // workspace layout
    char* p = (char*)d_ws;
    ushort* w_bf = (ushort*)p;                 p += 3 * 65536 * sizeof(ushort);   // 384 KB
    ushort* qp   = (ushort*)p;                 p += (size_t)BB * SS * DN * 2;     // 1 MB
    ushort* kp   = (ushort*)p;                 p += (size_t)BB * SS * DN * 2;     // 1 MB
    ushort* vpT  = (ushort*)p;                 p += (size_t)BB * SS * DN * 2;     // 1 MB
    size_t fixed = (size_t)(p - (char*)d_ws);

    int split = 8;
    while (split > 1 &&
           fixed + (size_t)split * ((size_t)BB * SS * 2 * 4 + (size_t)BB * SS * DN * 4) > ws_size)
        split >>= 1;

    float* part_ml = (float*)p;                p += (size_t)split * BB * SS * 2 * 4;
    float* part_O  = (float*)p;

    int keys_per_slice = SS / split;

    prep_w<<<192, 256, 0, stream>>>(wq, wk, wv, w_bf);
    proj_kernel<<<dim3(256, 3), 128, 0, stream>>>(q, k, v, w_bf, bq, bk, bv, qp, kp, vpT);
    flash_kernel<<<128 * split, 256, 0, stream>>>(mask, qp, kp, vpT, part_O, part_ml,
                                                  split, keys_per_slice);
    combine_kernel<<<(BB * SS) / 4, 256, 0, stream>>>(part_O, part_ml, out, split);
}